// Round 10
// baseline (1798.394 us; speedup 1.0000x reference)
//
#include <hip/hip_runtime.h>
#include <hip/hip_bf16.h>

typedef __bf16 bf16x8 __attribute__((ext_vector_type(8)));
typedef float  f32x4  __attribute__((ext_vector_type(4)));
typedef short  s16x4  __attribute__((ext_vector_type(4)));
typedef unsigned short u16;

#define L2E 1.44269504088896f
#define SCHED __builtin_amdgcn_sched_barrier(0)

static __device__ __forceinline__ u16 f2bf(float f) {
  unsigned u = __builtin_bit_cast(unsigned, f);
  u += 0x7fffu + ((u >> 16) & 1u);
  return (u16)(u >> 16);
}

static __device__ __forceinline__ void gld_lds16(const void* g, void* l) {
  __builtin_amdgcn_global_load_lds((const __attribute__((address_space(1))) unsigned*)g,
                                   (__attribute__((address_space(3))) unsigned*)l, 16, 0, 0);
}

// ---------------------------------------------------------------------------
__global__ __launch_bounds__(256)
void cvtk(const float* __restrict__ s, u16* __restrict__ d, int n) {
  const int i = (blockIdx.x * 256 + threadIdx.x) * 4;
  if (i >= n) return;
  const float4 f = *(const float4*)(s + i);
  s16x4 p;
  p[0] = (short)f2bf(f.x); p[1] = (short)f2bf(f.y);
  p[2] = (short)f2bf(f.z); p[3] = (short)f2bf(f.w);
  *(s16x4*)(d + i) = p;
}

// ---------------------------------------------------------------------------
__global__ __launch_bounds__(256)
void lnk(const float* __restrict__ x, const float* __restrict__ gw,
         const float* __restrict__ bw, u16* __restrict__ y,
         u16* __restrict__ xv, int viewmajor) {
  const int lane = threadIdx.x & 63;
  const int tok = blockIdx.x * 4 + (threadIdx.x >> 6);
  const float* xr = x + (size_t)tok * 768;
  float4 v[3];
  float s = 0.f, sq = 0.f;
#pragma unroll
  for (int j = 0; j < 3; ++j) {
    v[j] = *(const float4*)(xr + j * 256 + lane * 4);
    s  += v[j].x + v[j].y + v[j].z + v[j].w;
    sq += v[j].x * v[j].x + v[j].y * v[j].y + v[j].z * v[j].z + v[j].w * v[j].w;
  }
#pragma unroll
  for (int o = 1; o < 64; o <<= 1) { s += __shfl_xor(s, o); sq += __shfl_xor(sq, o); }
  const float mean = s * (1.f / 768.f);
  const float var  = sq * (1.f / 768.f) - mean * mean;
  const float rstd = rsqrtf(var + 1e-5f);
  size_t yrow = (size_t)tok;
  if (viewmajor) {
    const int b_ = tok >> 14, vv = (tok >> 13) & 1, l_ = tok & 8191;
    yrow = ((size_t)((vv << 2) + b_) << 13) + l_;
  }
#pragma unroll
  for (int j = 0; j < 3; ++j) {
    const float4 g4 = *(const float4*)(gw + j * 256 + lane * 4);
    const float4 b4 = *(const float4*)(bw + j * 256 + lane * 4);
    s16x4 py;
    py[0] = (short)f2bf((v[j].x - mean) * rstd * g4.x + b4.x);
    py[1] = (short)f2bf((v[j].y - mean) * rstd * g4.y + b4.y);
    py[2] = (short)f2bf((v[j].z - mean) * rstd * g4.z + b4.z);
    py[3] = (short)f2bf((v[j].w - mean) * rstd * g4.w + b4.w);
    *(s16x4*)(y + yrow * 768 + j * 256 + lane * 4) = py;
    if (xv) {
      s16x4 px;
      px[0] = (short)f2bf(v[j].x); px[1] = (short)f2bf(v[j].y);
      px[2] = (short)f2bf(v[j].z); px[3] = (short)f2bf(v[j].w);
      *(s16x4*)(xv + yrow * 768 + j * 256 + lane * 4) = px;
    }
  }
}

// ---------------------------------------------------------------------------
// 2-block/CU GEMM. Block = 256 thr (4 waves, 2Mx2N of 128x64), tile 256x128,
// BK=32, double-buffered LDS 48 KB (A 2x16KB @0, B 2x8KB @32768) -> 2 blocks
// resident per CU; one block's stage/drain/epilogue overlaps the other's MFMA.
// Per K-tile: stage next (6 gld_lds) -> vmcnt(6) counted (in-flight tile
// never drained) -> barrier -> 12 ds_read_b128 + 32 MFMA -> barrier.
// LDS swizzle for 64B rows: chunk ^= (row>>1)&3 (2-way only; row&7-style
// would be 4-way here). Inverse swizzle on global source.
// Runtime sub/mode: up to 6 sub-GEMMs fused per dispatch (tail-free grids).
// ---------------------------------------------------------------------------
struct GArgs {
  const u16* A[6]; const u16* B[6]; const float* bias[6]; void* C[6];
  int mode[6]; int vv[6];
  int bps, N, K;
  const float* xres; const int* idxp;
};

__global__ __launch_bounds__(256, 2)
void gemmk(GArgs ga) {
  __shared__ char lds[49152];
  const int t = threadIdx.x;
  const int lane = t & 63;
  const int wid = t >> 6;              // 0..3
  const int wm = wid >> 1, wn = wid & 1;

  const int sub = blockIdx.x / ga.bps;
  const int local = blockIdx.x - sub * ga.bps;
  const u16* A = ga.A[sub];
  const u16* B = ga.B[sub];
  const float* bias = ga.bias[sub];
  void* Cp = ga.C[sub];
  const int mode = ga.mode[sub];
  const int vview = ga.vv[sub];
  const int N = ga.N, K = ga.K;

  // XCD-bijective swizzle within sub (bps % 8 == 0)
  const int cpx = ga.bps >> 3;
  const int bid = (local & 7) * cpx + (local >> 3);
  const int Ntiles = N >> 7;
  const int PPB = Ntiles << 3;         // 8 m-tiles per panel
  const int panel = bid / PPB;
  const int rem = bid - panel * PPB;
  const int nt = rem >> 3;
  const int mt = (panel << 3) + (rem & 7);

  // staging: thread covers row r0 = t>>2 (+ i*64), dest chunk t&3;
  // source chunk inverse-swizzled: LDS[row][c] = global[row][c ^ ((row>>1)&3)]
  const int r0 = t >> 2;
  const int csrc = (t & 3) ^ ((r0 >> 1) & 3);
  const u16* Asrc = A + (size_t)(mt * 256 + r0) * K + csrc * 8;
  const u16* Bsrc = B + (size_t)(nt * 128 + r0) * K + csrc * 8;
  const int wdst = wid << 10;

  auto stage = [&](int d, int kt) {
#pragma unroll
    for (int i = 0; i < 4; ++i)
      gld_lds16(Asrc + (size_t)(i * 64) * K + kt * 32,
                (char*)lds + d * 16384 + i * 4096 + wdst);
#pragma unroll
    for (int i = 0; i < 2; ++i)
      gld_lds16(Bsrc + (size_t)(i * 64) * K + kt * 32,
                (char*)lds + 32768 + d * 8192 + i * 4096 + wdst);
  };

  const int c15 = lane & 15, g = lane >> 4;
  bf16x8 av[8], bv[4];
  auto rdA = [&](int d) {
#pragma unroll
    for (int m = 0; m < 8; ++m) {
      const int row = wm * 128 + m * 16 + c15;
      av[m] = *(const bf16x8*)((char*)lds + d * 16384 + row * 64 +
                               ((g ^ ((row >> 1) & 3)) << 4));
    }
  };
  auto rdB = [&](int d) {
#pragma unroll
    for (int n = 0; n < 4; ++n) {
      const int row = wn * 64 + n * 16 + c15;
      bv[n] = *(const bf16x8*)((char*)lds + 32768 + d * 8192 + row * 64 +
                               ((g ^ ((row >> 1) & 3)) << 4));
    }
  };

  f32x4 acc[8][4] = {};
  const int nk = K >> 5;

  stage(0, 0);
#pragma unroll 2
  for (int kt = 0; kt < nk; ++kt) {
    const int d = kt & 1;
    if (kt + 1 < nk) {
      stage(d ^ 1, kt + 1);
      asm volatile("s_waitcnt vmcnt(6)" ::: "memory");
    } else {
      asm volatile("s_waitcnt vmcnt(0)" ::: "memory");
    }
    __builtin_amdgcn_s_barrier();
    SCHED;
    rdA(d); rdB(d);
    __builtin_amdgcn_s_setprio(1);
#pragma unroll
    for (int m = 0; m < 8; ++m)
#pragma unroll
      for (int n = 0; n < 4; ++n)
        acc[m][n] = __builtin_amdgcn_mfma_f32_16x16x32_bf16(av[m], bv[n], acc[m][n], 0, 0, 0);
    __builtin_amdgcn_s_setprio(0);
    SCHED;
    __builtin_amdgcn_s_barrier();
  }

  const int shift = (mode == 2 && (ga.idxp[0] & 1)) ? 256 : 0;
  const int rb0 = mt * 256 + wm * 128 + (g << 2);
  const int cbase = nt * 128 + wn * 64 + c15;
#pragma unroll
  for (int mi = 0; mi < 8; ++mi) {
    const int row = rb0 + mi * 16;
#pragma unroll
    for (int nj = 0; nj < 4; ++nj) {
      const int col = cbase + nj * 16;
      const float bvv = bias[col];
      if (mode == 0) {
        u16* C = (u16*)Cp;
#pragma unroll
        for (int r = 0; r < 4; ++r)
          C[(size_t)(row + r) * N + col] = f2bf(acc[mi][nj][r] + bvv);
      } else if (mode == 1) {
        u16* C = (u16*)Cp;
        const int hh = col >> 6, dd = col & 63;
        const int b_ = row >> 13, l_ = row & 8191;
        s16x4 pk;
#pragma unroll
        for (int r = 0; r < 4; ++r) pk[r] = (short)f2bf(acc[mi][nj][r] + bvv);
        *(s16x4*)(C + (((size_t)((b_ * 12 + hh) << 6) + dd) << 13) + l_) = pk;
      } else if (mode == 2) {
        float* C = (float*)Cp;
        const int b_ = row >> 13, p_ = row & 8191;
        const int l0 = (p_ - shift) & 8191;
        const size_t rbase = ((size_t)((b_ << 1) + vview) << 13) + l0;
#pragma unroll
        for (int r = 0; r < 4; ++r) {
          const size_t idx = (rbase + r) * 768 + col;
          C[idx] = ga.xres[idx] + acc[mi][nj][r] + bvv;
        }
      } else if (mode == 3) {
        u16* C = (u16*)Cp;
#pragma unroll
        for (int r = 0; r < 4; ++r) {
          const float u = acc[mi][nj][r] + bvv;
          const float e = __builtin_amdgcn_exp2f(-2.45546693f * u);
          C[(size_t)(row + r) * N + col] = f2bf(u / (1.f + e));
        }
      } else {
        float* C = (float*)Cp;
#pragma unroll
        for (int r = 0; r < 4; ++r) {
          const size_t idx = (size_t)(row + r) * 768 + col;
          C[idx] = C[idx] + acc[mi][nj][r] + bvv;
        }
      }
    }
  }
}

// ---------------------------------------------------------------------------
// Windowed cross-view attention, LDS-staged K/V (unchanged from r9;
// refcheck-passing). Block = one (att,b,win,head), 8 waves = 512 queries.
// ---------------------------------------------------------------------------
__global__ __launch_bounds__(512, 2)
void attnk(const u16* __restrict__ Q1, const u16* __restrict__ K1, const u16* __restrict__ V1,
           const u16* __restrict__ Q2, const u16* __restrict__ K2, const u16* __restrict__ V2,
           u16* __restrict__ O, const int* __restrict__ idxp) {
  __shared__ char lds[131072];   // K @0 (64 KB), V^T @65536 (64 KB)
  const int t = threadIdx.x;
  const int lane = t & 63;
  const int c = lane & 15, g = lane >> 4;
  const int wid = t >> 6;
  int bb = blockIdx.x;
  const int h = bb % 12; bb /= 12;
  const int w = bb & 15; bb >>= 4;
  const int b = bb & 3;
  const int a = bb >> 2;
  const int shift = (idxp[0] & 1) ? 256 : 0;

  const u16* Q  = a ? Q2 : Q1;
  const u16* Kb = a ? K2 : K1;
  const u16* Vt = a ? V2 : V1;
  const int kbase = b * 8192 + w * 512;
  const u16* Vts = Vt + ((size_t)(b * 12 + h) << 19);

  const int qrow0 = b * 8192 + w * 512 + wid * 64;
  bf16x8 qf[4][2];
#pragma unroll
  for (int q = 0; q < 4; ++q)
#pragma unroll
    for (int hf = 0; hf < 2; ++hf)
      qf[q][hf] = *(const bf16x8*)(Q + (size_t)(qrow0 + q * 16 + c) * 768 + h * 64 + hf * 32 + g * 8);

  {
    const int r0 = t >> 3, ch = t & 7;
    char* kdst = (char*)lds + (wid << 10);
#pragma unroll
    for (int p = 0; p < 8; ++p) {
      const int row = p * 64 + r0;
      gld_lds16(Kb + (size_t)(kbase + row) * 768 + h * 64 + ((ch ^ (row & 7)) << 3),
                kdst + p * 8192);
    }
    char* vdst = (char*)lds + 65536 + (wid << 10);
#pragma unroll
    for (int p = 0; p < 8; ++p) {
      const int vrow = p * 8 + wid;
      const int cg = lane ^ (vrow & 7);
      const int l = (w * 512 + cg * 8 - shift) & 8191;
      gld_lds16(Vts + (size_t)vrow * 8192 + l, vdst + p * 8192);
    }
  }
  __syncthreads();

  f32x4 oacc[4][4] = {};
  f32x4 psum[4] = {};
  const float CEXP = 0.125f * L2E;
  const char* LK = (char*)lds;
  const char* LV = (char*)lds + 65536;

  for (int kt = 0; kt < 32; ++kt) {
    const int krow = kt * 16 + c;
    const int ksw = krow & 7;
    const bf16x8 kf0 = *(const bf16x8*)(LK + krow * 128 + ((g ^ ksw) << 4));
    const bf16x8 kf1 = *(const bf16x8*)(LK + krow * 128 + (((4 | g) ^ ksw) << 4));
    s16x4 vf[4];
#pragma unroll
    for (int df = 0; df < 4; ++df) {
      const int vr = df * 16 + c;
      vf[df] = *(const s16x4*)(LV + vr * 1024 +
                               (((kt * 2 + (g >> 1)) ^ (vr & 7)) << 4) + ((g & 1) << 3));
    }

    const f32x4 z = {0.f, 0.f, 0.f, 0.f};
    s16x4 pk[4];
#pragma unroll
    for (int q = 0; q < 4; ++q) {
      f32x4 sc2 = __builtin_amdgcn_mfma_f32_16x16x32_bf16(kf0, qf[q][0], z, 0, 0, 0);
      sc2 = __builtin_amdgcn_mfma_f32_16x16x32_bf16(kf1, qf[q][1], sc2, 0, 0, 0);
      f32x4 pv;
      pv[0] = __builtin_amdgcn_exp2f(sc2[0] * CEXP);
      pv[1] = __builtin_amdgcn_exp2f(sc2[1] * CEXP);
      pv[2] = __builtin_amdgcn_exp2f(sc2[2] * CEXP);
      pv[3] = __builtin_amdgcn_exp2f(sc2[3] * CEXP);
      psum[q] += pv;
      pk[q][0] = (short)f2bf(pv[0]);
      pk[q][1] = (short)f2bf(pv[1]);
      pk[q][2] = (short)f2bf(pv[2]);
      pk[q][3] = (short)f2bf(pv[3]);
    }
#pragma unroll
    for (int df = 0; df < 4; ++df)
#pragma unroll
      for (int q = 0; q < 4; ++q)
        oacc[df][q] = __builtin_amdgcn_mfma_f32_16x16x16bf16_1k(vf[df], pk[q], oacc[df][q], 0, 0, 0);
  }

  const size_t orow0 = (size_t)(a * 32768 + qrow0);
#pragma unroll
  for (int q = 0; q < 4; ++q) {
    float ss = psum[q][0] + psum[q][1] + psum[q][2] + psum[q][3];
    ss += __shfl_xor(ss, 16);
    ss += __shfl_xor(ss, 32);
    const float inv = 1.f / ss;
#pragma unroll
    for (int df = 0; df < 4; ++df) {
      s16x4 po;
#pragma unroll
      for (int r = 0; r < 4; ++r) po[r] = (short)f2bf(oacc[df][q][r] * inv);
      *(s16x4*)(O + (orow0 + q * 16 + c) * 768 + h * 64 + df * 16 + g * 4) = po;
    }
  }
}

// ---------------------------------------------------------------------------
extern "C" void kernel_launch(void* const* d_in, const int* in_sizes, int n_in,
                              void* d_out, int out_size, void* d_ws, size_t ws_size,
                              hipStream_t stream) {
  const float* x       = (const float*)d_in[0];
  const float* ln1_g   = (const float*)d_in[1];
  const float* ln1_b   = (const float*)d_in[2];
  const float* ln2_g   = (const float*)d_in[3];
  const float* ln2_b   = (const float*)d_in[4];
  const float* a1_wqkv = (const float*)d_in[5];
  const float* a1_bqkv = (const float*)d_in[6];
  const float* a1_wo   = (const float*)d_in[7];
  const float* a1_bo   = (const float*)d_in[8];
  const float* a2_wqkv = (const float*)d_in[9];
  const float* a2_bqkv = (const float*)d_in[10];
  const float* a2_wo   = (const float*)d_in[11];
  const float* a2_bo   = (const float*)d_in[12];
  const float* fc_w    = (const float*)d_in[13];
  const float* fc_b    = (const float*)d_in[14];
  const float* proj_w  = (const float*)d_in[15];
  const float* proj_b  = (const float*)d_in[16];
  const int*   idxp    = (const int*)d_in[17];
  float* out = (float*)d_out;

  u16* p = (u16*)d_ws;
  u16* w1  = p; p += (size_t)2304 * 768;
  u16* w2  = p; p += (size_t)2304 * 768;
  u16* wo1 = p; p += (size_t)768 * 768;
  u16* wo2 = p; p += (size_t)768 * 768;
  u16* fcw = p; p += (size_t)3072 * 768;
  u16* pjw = p; p += (size_t)768 * 3072;
  u16* y   = p; p += (size_t)65536 * 768;
  u16* xv  = p; p += (size_t)65536 * 768;
  u16* Q1  = p; p += (size_t)32768 * 768;
  u16* K1  = p; p += (size_t)32768 * 768;
  u16* V1  = p; p += (size_t)32768 * 768;
  u16* Q2  = p; p += (size_t)32768 * 768;
  u16* K2  = p; p += (size_t)32768 * 768;
  u16* V2  = p; p += (size_t)32768 * 768;
  u16* Ob  = p; p += (size_t)65536 * 768;
  u16* hb  = Q1;  // MLP hidden aliases Q1..Ob

  cvtk<<<1728, 256, 0, stream>>>(a1_wqkv, w1, 2304 * 768);
  cvtk<<<1728, 256, 0, stream>>>(a2_wqkv, w2, 2304 * 768);
  cvtk<<<576,  256, 0, stream>>>(a1_wo, wo1, 768 * 768);
  cvtk<<<576,  256, 0, stream>>>(a2_wo, wo2, 768 * 768);
  cvtk<<<2304, 256, 0, stream>>>(fc_w, fcw, 3072 * 768);
  cvtk<<<2304, 256, 0, stream>>>(proj_w, pjw, 768 * 3072);

  lnk<<<16384, 256, 0, stream>>>(x, ln1_g, ln1_b, y, xv, 1);

  const size_t VS = (size_t)32768 * 768;

  // fused QKV: 6 sub-GEMMs (M=32768, N=768, K=768) -> 4608 blocks
  {
    GArgs ga = {};
    ga.A[0] = y;       ga.B[0] = w1;                 ga.bias[0] = a1_bqkv;        ga.C[0] = Q1; ga.mode[0] = 0;
    ga.A[1] = y + VS;  ga.B[1] = w1 + 768 * 768;     ga.bias[1] = a1_bqkv + 768;  ga.C[1] = K1; ga.mode[1] = 0;
    ga.A[2] = xv;      ga.B[2] = w1 + 2 * 768 * 768; ga.bias[2] = a1_bqkv + 1536; ga.C[2] = V1; ga.mode[2] = 1;
    ga.A[3] = y + VS;  ga.B[3] = w2;                 ga.bias[3] = a2_bqkv;        ga.C[3] = Q2; ga.mode[3] = 0;
    ga.A[4] = y;       ga.B[4] = w2 + 768 * 768;     ga.bias[4] = a2_bqkv + 768;  ga.C[4] = K2; ga.mode[4] = 0;
    ga.A[5] = xv + VS; ga.B[5] = w2 + 2 * 768 * 768; ga.bias[5] = a2_bqkv + 1536; ga.C[5] = V2; ga.mode[5] = 1;
    ga.bps = 768; ga.N = 768; ga.K = 768; ga.xres = nullptr; ga.idxp = idxp;
    gemmk<<<4608, 256, 0, stream>>>(ga);
  }

  attnk<<<1536, 512, 0, stream>>>(Q1, K1, V1, Q2, K2, V2, Ob, idxp);

  // fused out-proj + residual -> d_out (2 subs)
  {
    GArgs ga = {};
    ga.A[0] = Ob;      ga.B[0] = wo1; ga.bias[0] = a1_bo; ga.C[0] = out; ga.mode[0] = 2; ga.vv[0] = 0;
    ga.A[1] = Ob + VS; ga.B[1] = wo2; ga.bias[1] = a2_bo; ga.C[1] = out; ga.mode[1] = 2; ga.vv[1] = 1;
    ga.bps = 768; ga.N = 768; ga.K = 768; ga.xres = x; ga.idxp = idxp;
    gemmk<<<1536, 256, 0, stream>>>(ga);
  }

  lnk<<<16384, 256, 0, stream>>>(out, ln2_g, ln2_b, y, nullptr, 0);

  // FC + GELU: M=65536, N=3072 -> 6144 blocks
  {
    GArgs ga = {};
    ga.A[0] = y; ga.B[0] = fcw; ga.bias[0] = fc_b; ga.C[0] = hb; ga.mode[0] = 3;
    ga.bps = 6144; ga.N = 3072; ga.K = 768; ga.xres = nullptr; ga.idxp = idxp;
    gemmk<<<6144, 256, 0, stream>>>(ga);
  }

  // proj + residual: M=65536, N=768, K=3072 -> 1536 blocks
  {
    GArgs ga = {};
    ga.A[0] = hb; ga.B[0] = pjw; ga.bias[0] = proj_b; ga.C[0] = out; ga.mode[0] = 4;
    ga.bps = 1536; ga.N = 768; ga.K = 3072; ga.xres = nullptr; ga.idxp = idxp;
    gemmk<<<1536, 256, 0, stream>>>(ga);
  }
}

// Round 11
// 1557.482 us; speedup vs baseline: 1.1547x; 1.1547x over previous
//
#include <hip/hip_runtime.h>
#include <hip/hip_bf16.h>

typedef __bf16 bf16x8 __attribute__((ext_vector_type(8)));
typedef float  f32x4  __attribute__((ext_vector_type(4)));
typedef short  s16x4  __attribute__((ext_vector_type(4)));
typedef unsigned short u16;

#define L2E 1.44269504088896f
#define SBAR  __builtin_amdgcn_s_barrier()
#define SCHED __builtin_amdgcn_sched_barrier(0)

static __device__ __forceinline__ u16 f2bf(float f) {
  unsigned u = __builtin_bit_cast(unsigned, f);
  u += 0x7fffu + ((u >> 16) & 1u);
  return (u16)(u >> 16);
}

static __device__ __forceinline__ void gld_lds16(const void* g, void* l) {
  __builtin_amdgcn_global_load_lds((const __attribute__((address_space(1))) unsigned*)g,
                                   (__attribute__((address_space(3))) unsigned*)l, 16, 0, 0);
}

// ---------------------------------------------------------------------------
// fused fp32 -> bf16 conversion of all 6 weight tensors (one dispatch)
// ---------------------------------------------------------------------------
struct CArgs { const float* s[6]; u16* d[6]; int cum[6]; };

__global__ __launch_bounds__(256)
void cvtk6(CArgs ca) {
  const int i = (blockIdx.x * 256 + threadIdx.x) * 4;
  int seg = 0, base = 0;
#pragma unroll
  for (int j = 0; j < 6; ++j)
    if (i >= ca.cum[j]) { seg = j + 1; base = ca.cum[j]; }
  if (seg >= 6) return;
  const int local = i - base;
  const float4 f = *(const float4*)(ca.s[seg] + local);
  s16x4 p;
  p[0] = (short)f2bf(f.x); p[1] = (short)f2bf(f.y);
  p[2] = (short)f2bf(f.z); p[3] = (short)f2bf(f.w);
  *(s16x4*)(ca.d[seg] + local) = p;
}

// ---------------------------------------------------------------------------
__global__ __launch_bounds__(256)
void lnk(const float* __restrict__ x, const float* __restrict__ gw,
         const float* __restrict__ bw, u16* __restrict__ y,
         u16* __restrict__ xv, int viewmajor) {
  const int lane = threadIdx.x & 63;
  const int tok = blockIdx.x * 4 + (threadIdx.x >> 6);
  const float* xr = x + (size_t)tok * 768;
  float4 v[3];
  float s = 0.f, sq = 0.f;
#pragma unroll
  for (int j = 0; j < 3; ++j) {
    v[j] = *(const float4*)(xr + j * 256 + lane * 4);
    s  += v[j].x + v[j].y + v[j].z + v[j].w;
    sq += v[j].x * v[j].x + v[j].y * v[j].y + v[j].z * v[j].z + v[j].w * v[j].w;
  }
#pragma unroll
  for (int o = 1; o < 64; o <<= 1) { s += __shfl_xor(s, o); sq += __shfl_xor(sq, o); }
  const float mean = s * (1.f / 768.f);
  const float var  = sq * (1.f / 768.f) - mean * mean;
  const float rstd = rsqrtf(var + 1e-5f);
  size_t yrow = (size_t)tok;
  if (viewmajor) {
    const int b_ = tok >> 14, vv = (tok >> 13) & 1, l_ = tok & 8191;
    yrow = ((size_t)((vv << 2) + b_) << 13) + l_;
  }
#pragma unroll
  for (int j = 0; j < 3; ++j) {
    const float4 g4 = *(const float4*)(gw + j * 256 + lane * 4);
    const float4 b4 = *(const float4*)(bw + j * 256 + lane * 4);
    s16x4 py;
    py[0] = (short)f2bf((v[j].x - mean) * rstd * g4.x + b4.x);
    py[1] = (short)f2bf((v[j].y - mean) * rstd * g4.y + b4.y);
    py[2] = (short)f2bf((v[j].z - mean) * rstd * g4.z + b4.z);
    py[3] = (short)f2bf((v[j].w - mean) * rstd * g4.w + b4.w);
    *(s16x4*)(y + yrow * 768 + j * 256 + lane * 4) = py;
    if (xv) {
      s16x4 px;
      px[0] = (short)f2bf(v[j].x); px[1] = (short)f2bf(v[j].y);
      px[2] = (short)f2bf(v[j].z); px[3] = (short)f2bf(v[j].w);
      *(s16x4*)(xv + yrow * 768 + j * 256 + lane * 4) = px;
    }
  }
}

// ===========================================================================
// 8-phase GEMM core (r7 structure, best measured). BM=BN=256, BK=64,
// 8 waves (2Mx4N, per-wave 128x64), 2 K-tiles/iter, vmcnt(6) at P4/P8 only,
// XOR-swizzled LDS (inverse swizzle on global source of global_load_lds).
// Shared between the template<MODE> kernel (FC, proj) and the fused
// multi-sub kernel (QKV x6, out-proj x2) below.
// ===========================================================================
#define GEMM_CORE(A, B, Kc)                                                      \
  const int t = threadIdx.x;                                                     \
  const int lane = t & 63;                                                       \
  const int wid = t >> 6;                                                        \
  const int wm = wid >> 2, wn = wid & 3;                                         \
  const int urow = t >> 3;                                                       \
  const int koff = ((t & 7) ^ (urow & 7)) << 3;                                  \
  const u16* Asrc = A + (size_t)(mt * 256 + urow) * (Kc) + koff;                 \
  const u16* Bsrc = B + (size_t)(nt * 256 + urow) * (Kc) + koff;                 \
  const int wdst = wid << 10;                                                    \
  auto stgA = [&](int d, int kt, int u0) {                                       \
    char* base = (char*)lds + d * 32768 + wdst;                                  \
    gld_lds16(Asrc + (size_t)(u0 * 64) * (Kc) + kt * 64, base + u0 * 8192);      \
    gld_lds16(Asrc + (size_t)(u0 * 64 + 64) * (Kc) + kt * 64,                    \
              base + u0 * 8192 + 8192);                                          \
  };                                                                             \
  auto stgB = [&](int d, int kt, int u0) {                                       \
    char* base = (char*)lds + 65536 + d * 32768 + wdst;                          \
    gld_lds16(Bsrc + (size_t)(u0 * 64) * (Kc) + kt * 64, base + u0 * 8192);      \
    gld_lds16(Bsrc + (size_t)(u0 * 64 + 64) * (Kc) + kt * 64,                    \
              base + u0 * 8192 + 8192);                                          \
  };                                                                             \
  const int c15 = lane & 15, g = lane >> 4;                                      \
  const int axor = c15 & 7;                                                      \
  const char* LAb = (char*)lds + (wm * 128 + c15) * 128;                         \
  const char* LBb = (char*)lds + 65536 + (wn * 64 + c15) * 128;                  \
  bf16x8 av[4][2], bv[4][2];                                                     \
  auto rdA = [&](int d, int mh) {                                                \
    _Pragma("unroll")                                                            \
    for (int m = 0; m < 4; ++m)                                                  \
      _Pragma("unroll")                                                          \
      for (int ks = 0; ks < 2; ++ks)                                             \
        av[m][ks] = *(const bf16x8*)(LAb + d * 32768 +                           \
            (mh * 64 + m * 16) * 128 + (((ks << 2) | g) ^ axor) * 16);           \
  };                                                                             \
  auto rdB = [&](int d) {                                                        \
    _Pragma("unroll")                                                            \
    for (int n = 0; n < 4; ++n)                                                  \
      _Pragma("unroll")                                                          \
      for (int ks = 0; ks < 2; ++ks)                                             \
        bv[n][ks] = *(const bf16x8*)(LBb + d * 32768 + (n * 16) * 128 +          \
            (((ks << 2) | g) ^ axor) * 16);                                      \
  };                                                                             \
  f32x4 acc[8][4] = {};                                                          \
  auto QD = [&](int mh, int nh) {                                                \
    __builtin_amdgcn_s_setprio(1);                                               \
    _Pragma("unroll")                                                            \
    for (int ks = 0; ks < 2; ++ks)                                               \
      _Pragma("unroll")                                                          \
      for (int m = 0; m < 4; ++m)                                                \
        _Pragma("unroll")                                                        \
        for (int n = 0; n < 2; ++n)                                              \
          acc[mh * 4 + m][nh * 2 + n] = __builtin_amdgcn_mfma_f32_16x16x32_bf16( \
              av[m][ks], bv[nh * 2 + n][ks], acc[mh * 4 + m][nh * 2 + n],        \
              0, 0, 0);                                                          \
    __builtin_amdgcn_s_setprio(0);                                               \
  };                                                                             \
  const int nk = (Kc) >> 6, niter = nk >> 1, last = nk - 1;                      \
  stgA(0, 0, 0); stgA(0, 0, 2); stgB(0, 0, 0); stgB(0, 0, 2);                    \
  stgB(1, 1, 0); stgB(1, 1, 2); stgA(1, 1, 0);                                   \
  asm volatile("s_waitcnt vmcnt(6)" ::: "memory");                               \
  SBAR; SCHED;                                                                   \
  for (int it = 0; it < niter; ++it) {                                           \
    const int i2 = it * 2;                                                       \
    const int t1 = (i2 + 1 < nk) ? i2 + 1 : last;                                \
    const int t2 = (i2 + 2 < nk) ? i2 + 2 : last;                                \
    const int t3 = (i2 + 3 < nk) ? i2 + 3 : last;                                \
    rdA(0, 0); rdB(0); stgA(1, t1, 2);                                           \
    SCHED; SBAR; SCHED; QD(0, 0); SCHED; SBAR; SCHED;                            \
    stgB(0, t2, 0);                                                              \
    SCHED; SBAR; SCHED; QD(0, 1); SCHED; SBAR; SCHED;                            \
    rdA(0, 1); stgB(0, t2, 2);                                                   \
    SCHED; SBAR; SCHED; QD(1, 1); SCHED; SBAR; SCHED;                            \
    stgA(0, t2, 0);                                                              \
    asm volatile("s_waitcnt vmcnt(6)" ::: "memory");                             \
    SCHED; SBAR; SCHED; QD(1, 0); SCHED; SBAR; SCHED;                            \
    rdA(1, 0); rdB(1); stgA(0, t2, 2);                                           \
    SCHED; SBAR; SCHED; QD(0, 0); SCHED; SBAR; SCHED;                            \
    stgB(1, t3, 0);                                                              \
    SCHED; SBAR; SCHED; QD(0, 1); SCHED; SBAR; SCHED;                            \
    rdA(1, 1); stgB(1, t3, 2);                                                   \
    SCHED; SBAR; SCHED; QD(1, 1); SCHED; SBAR; SCHED;                            \
    stgA(1, t3, 0);                                                              \
    asm volatile("s_waitcnt vmcnt(6)" ::: "memory");                             \
    SCHED; SBAR; SCHED; QD(1, 0); SCHED; SBAR; SCHED;                            \
  }

// epilogue shared (runtime mode; once per block)
#define GEMM_EPI(Nc, mode, Cp, bias, xres, idxp, vview)                          \
  const int shift = ((mode) == 2 && ((idxp)[0] & 1)) ? 256 : 0;                  \
  const int rb0 = mt * 256 + wm * 128 + (g << 2);                                \
  const int cbase = nt * 256 + wn * 64 + c15;                                    \
  _Pragma("unroll")                                                              \
  for (int mi = 0; mi < 8; ++mi) {                                               \
    const int row = rb0 + mi * 16;                                               \
    _Pragma("unroll")                                                            \
    for (int nj = 0; nj < 4; ++nj) {                                             \
      const int col = cbase + nj * 16;                                           \
      const float bvv = (bias)[col];                                             \
      if ((mode) == 0) {                                                         \
        u16* C = (u16*)(Cp);                                                     \
        _Pragma("unroll")                                                        \
        for (int r = 0; r < 4; ++r)                                              \
          C[(size_t)(row + r) * (Nc) + col] = f2bf(acc[mi][nj][r] + bvv);        \
      } else if ((mode) == 1) {                                                  \
        u16* C = (u16*)(Cp);                                                     \
        const int hh = col >> 6, dd = col & 63;                                  \
        const int b_ = row >> 13, l_ = row & 8191;                               \
        s16x4 pk;                                                                \
        _Pragma("unroll")                                                        \
        for (int r = 0; r < 4; ++r) pk[r] = (short)f2bf(acc[mi][nj][r] + bvv);   \
        *(s16x4*)(C + (((size_t)((b_ * 12 + hh) << 6) + dd) << 13) + l_) = pk;   \
      } else if ((mode) == 2) {                                                  \
        float* C = (float*)(Cp);                                                 \
        const int b_ = row >> 13, p_ = row & 8191;                               \
        const int l0 = (p_ - shift) & 8191;                                      \
        const size_t rbase = ((size_t)((b_ << 1) + (vview)) << 13) + l0;         \
        _Pragma("unroll")                                                        \
        for (int r = 0; r < 4; ++r) {                                            \
          const size_t idx = (rbase + r) * 768 + col;                            \
          C[idx] = (xres)[idx] + acc[mi][nj][r] + bvv;                           \
        }                                                                        \
      } else if ((mode) == 3) {                                                  \
        u16* C = (u16*)(Cp);                                                     \
        _Pragma("unroll")                                                        \
        for (int r = 0; r < 4; ++r) {                                            \
          const float u = acc[mi][nj][r] + bvv;                                  \
          const float e = __builtin_amdgcn_exp2f(-2.45546693f * u);              \
          C[(size_t)(row + r) * (Nc) + col] = f2bf(u / (1.f + e));               \
        }                                                                        \
      } else {                                                                   \
        float* C = (float*)(Cp);                                                 \
        _Pragma("unroll")                                                        \
        for (int r = 0; r < 4; ++r) {                                            \
          const size_t idx = (size_t)(row + r) * 768 + col;                      \
          C[idx] = C[idx] + acc[mi][nj][r] + bvv;                                \
        }                                                                        \
      }                                                                          \
    }                                                                            \
  }

// ---------------------------------------------------------------------------
// FC / proj GEMM: single sub, compile-time MODE, runtime N,K.
// ---------------------------------------------------------------------------
template<int MODE>
__global__ __launch_bounds__(512, 2)
void gemm_bt(const u16* __restrict__ A, const u16* __restrict__ B,
             const float* __restrict__ bias, void* __restrict__ Cp,
             int N, int K,
             const float* __restrict__ xres, const int* __restrict__ idxp,
             int vview) {
  __shared__ char lds[131072];
  const int cpx = gridDim.x >> 3;
  const int bid = (blockIdx.x & 7) * cpx + (blockIdx.x >> 3);
  const int Ntiles = N >> 8;
  const int PPB = Ntiles << 3;
  const int panel = bid / PPB;
  const int rem = bid - panel * PPB;
  const int nt = rem >> 3;
  const int mt = (panel << 3) + (rem & 7);
  GEMM_CORE(A, B, K)
  GEMM_EPI(N, MODE, Cp, bias, xres, idxp, vview)
}

// ---------------------------------------------------------------------------
// Fused multi-sub GEMM: N=K=768 hardcoded; up to 6 subs of 384 blocks each.
// (384 % 8 == 0 -> per-sub XCD swizzle valid under round-robin dispatch.)
// ---------------------------------------------------------------------------
struct GArgs {
  const u16* A[6]; const u16* B[6]; const float* bias[6]; void* C[6];
  int mode[6]; int vv[6];
  const float* xres; const int* idxp;
};

__global__ __launch_bounds__(512, 2)
void gemm_multi(GArgs ga) {
  __shared__ char lds[131072];
  const int sub = blockIdx.x / 384;
  const int local = blockIdx.x - sub * 384;
  const u16* A = ga.A[sub];
  const u16* B = ga.B[sub];
  const float* bias = ga.bias[sub];
  void* Cp = ga.C[sub];
  const int mode = ga.mode[sub];
  const int vview = ga.vv[sub];

  const int bid = (local & 7) * 48 + (local >> 3);
  // N=768: Ntiles=3, PPB=24
  const int panel = bid / 24;
  const int rem = bid - panel * 24;
  const int nt = rem >> 3;
  const int mt = (panel << 3) + (rem & 7);
  GEMM_CORE(A, B, 768)
  GEMM_EPI(768, mode, Cp, bias, ga.xres, ga.idxp, vview)
}

// ---------------------------------------------------------------------------
// Windowed cross-view attention, LDS-staged K/V (r9, refcheck-passing).
// ---------------------------------------------------------------------------
__global__ __launch_bounds__(512, 2)
void attnk(const u16* __restrict__ Q1, const u16* __restrict__ K1, const u16* __restrict__ V1,
           const u16* __restrict__ Q2, const u16* __restrict__ K2, const u16* __restrict__ V2,
           u16* __restrict__ O, const int* __restrict__ idxp) {
  __shared__ char lds[131072];
  const int t = threadIdx.x;
  const int lane = t & 63;
  const int c = lane & 15, g = lane >> 4;
  const int wid = t >> 6;
  int bb = blockIdx.x;
  const int h = bb % 12; bb /= 12;
  const int w = bb & 15; bb >>= 4;
  const int b = bb & 3;
  const int a = bb >> 2;
  const int shift = (idxp[0] & 1) ? 256 : 0;

  const u16* Q  = a ? Q2 : Q1;
  const u16* Kb = a ? K2 : K1;
  const u16* Vt = a ? V2 : V1;
  const int kbase = b * 8192 + w * 512;
  const u16* Vts = Vt + ((size_t)(b * 12 + h) << 19);

  const int qrow0 = b * 8192 + w * 512 + wid * 64;
  bf16x8 qf[4][2];
#pragma unroll
  for (int q = 0; q < 4; ++q)
#pragma unroll
    for (int hf = 0; hf < 2; ++hf)
      qf[q][hf] = *(const bf16x8*)(Q + (size_t)(qrow0 + q * 16 + c) * 768 + h * 64 + hf * 32 + g * 8);

  {
    const int r0 = t >> 3, ch = t & 7;
    char* kdst = (char*)lds + (wid << 10);
#pragma unroll
    for (int p = 0; p < 8; ++p) {
      const int row = p * 64 + r0;
      gld_lds16(Kb + (size_t)(kbase + row) * 768 + h * 64 + ((ch ^ (row & 7)) << 3),
                kdst + p * 8192);
    }
    char* vdst = (char*)lds + 65536 + (wid << 10);
#pragma unroll
    for (int p = 0; p < 8; ++p) {
      const int vrow = p * 8 + wid;
      const int cg = lane ^ (vrow & 7);
      const int l = (w * 512 + cg * 8 - shift) & 8191;
      gld_lds16(Vts + (size_t)vrow * 8192 + l, vdst + p * 8192);
    }
  }
  __syncthreads();

  f32x4 oacc[4][4] = {};
  f32x4 psum[4] = {};
  const float CEXP = 0.125f * L2E;
  const char* LK = (char*)lds;
  const char* LV = (char*)lds + 65536;

  for (int kt = 0; kt < 32; ++kt) {
    const int krow = kt * 16 + c;
    const int ksw = krow & 7;
    const bf16x8 kf0 = *(const bf16x8*)(LK + krow * 128 + ((g ^ ksw) << 4));
    const bf16x8 kf1 = *(const bf16x8*)(LK + krow * 128 + (((4 | g) ^ ksw) << 4));
    s16x4 vf[4];
#pragma unroll
    for (int df = 0; df < 4; ++df) {
      const int vr = df * 16 + c;
      vf[df] = *(const s16x4*)(LV + vr * 1024 +
                               (((kt * 2 + (g >> 1)) ^ (vr & 7)) << 4) + ((g & 1) << 3));
    }

    const f32x4 z = {0.f, 0.f, 0.f, 0.f};
    s16x4 pk[4];
#pragma unroll
    for (int q = 0; q < 4; ++q) {
      f32x4 sc2 = __builtin_amdgcn_mfma_f32_16x16x32_bf16(kf0, qf[q][0], z, 0, 0, 0);
      sc2 = __builtin_amdgcn_mfma_f32_16x16x32_bf16(kf1, qf[q][1], sc2, 0, 0, 0);
      f32x4 pv;
      pv[0] = __builtin_amdgcn_exp2f(sc2[0] * CEXP);
      pv[1] = __builtin_amdgcn_exp2f(sc2[1] * CEXP);
      pv[2] = __builtin_amdgcn_exp2f(sc2[2] * CEXP);
      pv[3] = __builtin_amdgcn_exp2f(sc2[3] * CEXP);
      psum[q] += pv;
      pk[q][0] = (short)f2bf(pv[0]);
      pk[q][1] = (short)f2bf(pv[1]);
      pk[q][2] = (short)f2bf(pv[2]);
      pk[q][3] = (short)f2bf(pv[3]);
    }
#pragma unroll
    for (int df = 0; df < 4; ++df)
#pragma unroll
      for (int q = 0; q < 4; ++q)
        oacc[df][q] = __builtin_amdgcn_mfma_f32_16x16x16bf16_1k(vf[df], pk[q], oacc[df][q], 0, 0, 0);
  }

  const size_t orow0 = (size_t)(a * 32768 + qrow0);
#pragma unroll
  for (int q = 0; q < 4; ++q) {
    float ss = psum[q][0] + psum[q][1] + psum[q][2] + psum[q][3];
    ss += __shfl_xor(ss, 16);
    ss += __shfl_xor(ss, 32);
    const float inv = 1.f / ss;
#pragma unroll
    for (int df = 0; df < 4; ++df) {
      s16x4 po;
#pragma unroll
      for (int r = 0; r < 4; ++r) po[r] = (short)f2bf(oacc[df][q][r] * inv);
      *(s16x4*)(O + (orow0 + q * 16 + c) * 768 + h * 64 + df * 16 + g * 4) = po;
    }
  }
}

// ---------------------------------------------------------------------------
extern "C" void kernel_launch(void* const* d_in, const int* in_sizes, int n_in,
                              void* d_out, int out_size, void* d_ws, size_t ws_size,
                              hipStream_t stream) {
  const float* x       = (const float*)d_in[0];
  const float* ln1_g   = (const float*)d_in[1];
  const float* ln1_b   = (const float*)d_in[2];
  const float* ln2_g   = (const float*)d_in[3];
  const float* ln2_b   = (const float*)d_in[4];
  const float* a1_wqkv = (const float*)d_in[5];
  const float* a1_bqkv = (const float*)d_in[6];
  const float* a1_wo   = (const float*)d_in[7];
  const float* a1_bo   = (const float*)d_in[8];
  const float* a2_wqkv = (const float*)d_in[9];
  const float* a2_bqkv = (const float*)d_in[10];
  const float* a2_wo   = (const float*)d_in[11];
  const float* a2_bo   = (const float*)d_in[12];
  const float* fc_w    = (const float*)d_in[13];
  const float* fc_b    = (const float*)d_in[14];
  const float* proj_w  = (const float*)d_in[15];
  const float* proj_b  = (const float*)d_in[16];
  const int*   idxp    = (const int*)d_in[17];
  float* out = (float*)d_out;

  u16* p = (u16*)d_ws;
  u16* w1  = p; p += (size_t)2304 * 768;
  u16* w2  = p; p += (size_t)2304 * 768;
  u16* wo1 = p; p += (size_t)768 * 768;
  u16* wo2 = p; p += (size_t)768 * 768;
  u16* fcw = p; p += (size_t)3072 * 768;
  u16* pjw = p; p += (size_t)768 * 3072;
  u16* y   = p; p += (size_t)65536 * 768;
  u16* xv  = p; p += (size_t)65536 * 768;
  u16* Q1  = p; p += (size_t)32768 * 768;
  u16* K1  = p; p += (size_t)32768 * 768;
  u16* V1  = p; p += (size_t)32768 * 768;
  u16* Q2  = p; p += (size_t)32768 * 768;
  u16* K2  = p; p += (size_t)32768 * 768;
  u16* V2  = p; p += (size_t)32768 * 768;
  u16* Ob  = p; p += (size_t)65536 * 768;
  u16* hb  = Q1;  // MLP hidden aliases Q1..Ob

  // fused weight conversion (one dispatch)
  {
    CArgs ca;
    ca.s[0] = a1_wqkv; ca.d[0] = w1;
    ca.s[1] = a2_wqkv; ca.d[1] = w2;
    ca.s[2] = a1_wo;   ca.d[2] = wo1;
    ca.s[3] = a2_wo;   ca.d[3] = wo2;
    ca.s[4] = fc_w;    ca.d[4] = fcw;
    ca.s[5] = proj_w;  ca.d[5] = pjw;
    int cum = 0;
    const int sz[6] = {2304*768, 2304*768, 768*768, 768*768, 3072*768, 768*3072};
    for (int j = 0; j < 6; ++j) { cum += sz[j]; ca.cum[j] = cum; }
    // NOTE: ca.s/ca.d bases must pair with local offsets: rebase pointers
    // so that "local = i - segbase" indexes from each tensor start.
    cvtk6<<<9216, 256, 0, stream>>>(ca);
  }

  lnk<<<16384, 256, 0, stream>>>(x, ln1_g, ln1_b, y, xv, 1);

  const size_t VS = (size_t)32768 * 768;

  // fused QKV: 6 subs x 384 blocks = 2304 (9 full generations)
  {
    GArgs ga = {};
    ga.A[0] = y;       ga.B[0] = w1;                 ga.bias[0] = a1_bqkv;        ga.C[0] = Q1; ga.mode[0] = 0;
    ga.A[1] = y + VS;  ga.B[1] = w1 + 768 * 768;     ga.bias[1] = a1_bqkv + 768;  ga.C[1] = K1; ga.mode[1] = 0;
    ga.A[2] = xv;      ga.B[2] = w1 + 2 * 768 * 768; ga.bias[2] = a1_bqkv + 1536; ga.C[2] = V1; ga.mode[2] = 1;
    ga.A[3] = y + VS;  ga.B[3] = w2;                 ga.bias[3] = a2_bqkv;        ga.C[3] = Q2; ga.mode[3] = 0;
    ga.A[4] = y;       ga.B[4] = w2 + 768 * 768;     ga.bias[4] = a2_bqkv + 768;  ga.C[4] = K2; ga.mode[4] = 0;
    ga.A[5] = xv + VS; ga.B[5] = w2 + 2 * 768 * 768; ga.bias[5] = a2_bqkv + 1536; ga.C[5] = V2; ga.mode[5] = 1;
    ga.xres = nullptr; ga.idxp = idxp;
    gemm_multi<<<2304, 512, 0, stream>>>(ga);
  }

  attnk<<<1536, 512, 0, stream>>>(Q1, K1, V1, Q2, K2, V2, Ob, idxp);

  // fused out-proj + residual: 2 subs x 384 = 768 blocks (3 full generations)
  {
    GArgs ga = {};
    ga.A[0] = Ob;      ga.B[0] = wo1; ga.bias[0] = a1_bo; ga.C[0] = out; ga.mode[0] = 2; ga.vv[0] = 0;
    ga.A[1] = Ob + VS; ga.B[1] = wo2; ga.bias[1] = a2_bo; ga.C[1] = out; ga.mode[1] = 2; ga.vv[1] = 1;
    ga.xres = x; ga.idxp = idxp;
    gemm_multi<<<768, 512, 0, stream>>>(ga);
  }

  lnk<<<16384, 256, 0, stream>>>(out, ln2_g, ln2_b, y, nullptr, 0);

  gemm_bt<3><<<3072, 512, 0, stream>>>(y, fcw, fc_b, hb, 3072, 768, nullptr, idxp, 0);

  gemm_bt<4><<<768, 512, 0, stream>>>(hb, pjw, proj_b, out, 768, 3072, nullptr, idxp, 0);
}

// Round 12
// 1456.371 us; speedup vs baseline: 1.2348x; 1.0694x over previous
//
#include <hip/hip_runtime.h>
#include <hip/hip_bf16.h>

typedef __bf16 bf16x8 __attribute__((ext_vector_type(8)));
typedef float  f32x4  __attribute__((ext_vector_type(4)));
typedef short  s16x4  __attribute__((ext_vector_type(4)));
typedef unsigned short u16;

#define L2E 1.44269504088896f
#define SBAR  __builtin_amdgcn_s_barrier()
#define SCHED __builtin_amdgcn_sched_barrier(0)

static __device__ __forceinline__ u16 f2bf(float f) {
  unsigned u = __builtin_bit_cast(unsigned, f);
  u += 0x7fffu + ((u >> 16) & 1u);
  return (u16)(u >> 16);
}

static __device__ __forceinline__ void gld_lds16(const void* g, void* l) {
  __builtin_amdgcn_global_load_lds((const __attribute__((address_space(1))) unsigned*)g,
                                   (__attribute__((address_space(3))) unsigned*)l, 16, 0, 0);
}

// ---------------------------------------------------------------------------
__global__ __launch_bounds__(256)
void cvtk(const float* __restrict__ s, u16* __restrict__ d, int n) {
  const int i = (blockIdx.x * 256 + threadIdx.x) * 4;
  if (i >= n) return;
  const float4 f = *(const float4*)(s + i);
  s16x4 p;
  p[0] = (short)f2bf(f.x); p[1] = (short)f2bf(f.y);
  p[2] = (short)f2bf(f.z); p[3] = (short)f2bf(f.w);
  *(s16x4*)(d + i) = p;
}

// ---------------------------------------------------------------------------
__global__ __launch_bounds__(256)
void lnk(const float* __restrict__ x, const float* __restrict__ gw,
         const float* __restrict__ bw, u16* __restrict__ y,
         u16* __restrict__ xv, int viewmajor) {
  const int lane = threadIdx.x & 63;
  const int tok = blockIdx.x * 4 + (threadIdx.x >> 6);
  const float* xr = x + (size_t)tok * 768;
  float4 v[3];
  float s = 0.f, sq = 0.f;
#pragma unroll
  for (int j = 0; j < 3; ++j) {
    v[j] = *(const float4*)(xr + j * 256 + lane * 4);
    s  += v[j].x + v[j].y + v[j].z + v[j].w;
    sq += v[j].x * v[j].x + v[j].y * v[j].y + v[j].z * v[j].z + v[j].w * v[j].w;
  }
#pragma unroll
  for (int o = 1; o < 64; o <<= 1) { s += __shfl_xor(s, o); sq += __shfl_xor(sq, o); }
  const float mean = s * (1.f / 768.f);
  const float var  = sq * (1.f / 768.f) - mean * mean;
  const float rstd = rsqrtf(var + 1e-5f);
  size_t yrow = (size_t)tok;
  if (viewmajor) {
    const int b_ = tok >> 14, vv = (tok >> 13) & 1, l_ = tok & 8191;
    yrow = ((size_t)((vv << 2) + b_) << 13) + l_;
  }
#pragma unroll
  for (int j = 0; j < 3; ++j) {
    const float4 g4 = *(const float4*)(gw + j * 256 + lane * 4);
    const float4 b4 = *(const float4*)(bw + j * 256 + lane * 4);
    s16x4 py;
    py[0] = (short)f2bf((v[j].x - mean) * rstd * g4.x + b4.x);
    py[1] = (short)f2bf((v[j].y - mean) * rstd * g4.y + b4.y);
    py[2] = (short)f2bf((v[j].z - mean) * rstd * g4.z + b4.z);
    py[3] = (short)f2bf((v[j].w - mean) * rstd * g4.w + b4.w);
    *(s16x4*)(y + yrow * 768 + j * 256 + lane * 4) = py;
    if (xv) {
      s16x4 px;
      px[0] = (short)f2bf(v[j].x); px[1] = (short)f2bf(v[j].y);
      px[2] = (short)f2bf(v[j].z); px[3] = (short)f2bf(v[j].w);
      *(s16x4*)(xv + yrow * 768 + j * 256 + lane * 4) = px;
    }
  }
}

// ---------------------------------------------------------------------------
// 8-phase GEMM, ONE barrier per phase. BM=BN=256, BK=64, 8 waves (2Mx4N,
// per-wave 128x64), 2 K-tiles/iter, vmcnt(6) at P4/P8 only, XOR-swizzled LDS.
// Phase = {ds_read subtile | stage} ; sched_barrier ; s_barrier ; 16 MFMA.
// Dropping the post-MFMA barrier lets wave B's phase-p+1 ds_reads/stages
// overlap wave A's phase-p MFMAs (LDS pipe || MFMA pipe across waves).
// Safety audit (all stage-vs-last-reader pairs keep >=1 barrier separation):
// P1 stg buf1.A23 (readers prev-P7) 2 bars | P2 stg buf0.B01 (P1) 1 bar |
// P3 stg buf0.B23 (P1) 2 | P4 stg buf0.A01 (P3) 1 | P5 stg buf0.A23 (P3) 2 |
// P6 stg buf1.B01 (P5) 1 | P7 stg buf1.B23 (P5) 2 | P8 stg buf1.A01 (P7) 1.
// MFMAs are register-only so floating past a barrier is harmless; WAR on
// av/bv pins each QD before the next rdA/rdB that rewrites its operands.
// vmcnt counts identical to r7 (refcheck-proven).
// ---------------------------------------------------------------------------
template<int MODE>
__global__ __launch_bounds__(512, 2)
void gemm_bt(const u16* __restrict__ A, const u16* __restrict__ B,
             const float* __restrict__ bias, void* __restrict__ Cp,
             int N, int K,
             const float* __restrict__ xres, const int* __restrict__ idxp,
             int vview) {
  __shared__ char lds[131072];
  const int t = threadIdx.x;
  const int lane = t & 63;
  const int wid = t >> 6;
  const int wm = wid >> 2, wn = wid & 3;

  const int cpx = gridDim.x >> 3;
  const int bid = (blockIdx.x & 7) * cpx + (blockIdx.x >> 3);
  const int Ntiles = N >> 8;
  const int PPB = Ntiles << 3;
  const int panel = bid / PPB;
  const int rem = bid - panel * PPB;
  const int nt = rem >> 3;
  const int mt = (panel << 3) + (rem & 7);

  const int urow = t >> 3;
  const int koff = ((t & 7) ^ (urow & 7)) << 3;
  const u16* Asrc = A + (size_t)(mt * 256 + urow) * K + koff;
  const u16* Bsrc = B + (size_t)(nt * 256 + urow) * K + koff;
  const int wdst = wid << 10;

  auto stgA = [&](int d, int kt, int u0) {
    char* base = (char*)lds + d * 32768 + wdst;
    gld_lds16(Asrc + (size_t)(u0 * 64) * K + kt * 64, base + u0 * 8192);
    gld_lds16(Asrc + (size_t)(u0 * 64 + 64) * K + kt * 64, base + u0 * 8192 + 8192);
  };
  auto stgB = [&](int d, int kt, int u0) {
    char* base = (char*)lds + 65536 + d * 32768 + wdst;
    gld_lds16(Bsrc + (size_t)(u0 * 64) * K + kt * 64, base + u0 * 8192);
    gld_lds16(Bsrc + (size_t)(u0 * 64 + 64) * K + kt * 64, base + u0 * 8192 + 8192);
  };

  const int c15 = lane & 15, g = lane >> 4;
  const int axor = c15 & 7;
  const char* LAb = (char*)lds + (wm * 128 + c15) * 128;
  const char* LBb = (char*)lds + 65536 + (wn * 64 + c15) * 128;
  bf16x8 av[4][2], bv[4][2];
  auto rdA = [&](int d, int mh) {
#pragma unroll
    for (int m = 0; m < 4; ++m)
#pragma unroll
      for (int ks = 0; ks < 2; ++ks)
        av[m][ks] = *(const bf16x8*)(LAb + d * 32768 + (mh * 64 + m * 16) * 128 +
                                     (((ks << 2) | g) ^ axor) * 16);
  };
  auto rdB = [&](int d) {
#pragma unroll
    for (int n = 0; n < 4; ++n)
#pragma unroll
      for (int ks = 0; ks < 2; ++ks)
        bv[n][ks] = *(const bf16x8*)(LBb + d * 32768 + (n * 16) * 128 +
                                     (((ks << 2) | g) ^ axor) * 16);
  };

  f32x4 acc[8][4] = {};
  auto QD = [&](int mh, int nh) {
    __builtin_amdgcn_s_setprio(1);
#pragma unroll
    for (int ks = 0; ks < 2; ++ks)
#pragma unroll
      for (int m = 0; m < 4; ++m)
#pragma unroll
        for (int n = 0; n < 2; ++n)
          acc[mh * 4 + m][nh * 2 + n] = __builtin_amdgcn_mfma_f32_16x16x32_bf16(
              av[m][ks], bv[nh * 2 + n][ks], acc[mh * 4 + m][nh * 2 + n], 0, 0, 0);
    __builtin_amdgcn_s_setprio(0);
  };

  const int nk = K >> 6, niter = nk >> 1, last = nk - 1;

  stgA(0, 0, 0); stgA(0, 0, 2); stgB(0, 0, 0); stgB(0, 0, 2);
  stgB(1, 1, 0); stgB(1, 1, 2); stgA(1, 1, 0);
  asm volatile("s_waitcnt vmcnt(6)" ::: "memory");
  SBAR;

  for (int it = 0; it < niter; ++it) {
    const int i2 = it * 2;
    const int t1 = (i2 + 1 < nk) ? i2 + 1 : last;
    const int t2 = (i2 + 2 < nk) ? i2 + 2 : last;
    const int t3 = (i2 + 3 < nk) ? i2 + 3 : last;

    // P1
    rdA(0, 0); rdB(0); stgA(1, t1, 2);
    SCHED; SBAR;
    QD(0, 0);
    // P2
    stgB(0, t2, 0);
    SCHED; SBAR;
    QD(0, 1);
    // P3
    rdA(0, 1); stgB(0, t2, 2);
    SCHED; SBAR;
    QD(1, 1);
    // P4
    stgA(0, t2, 0);
    asm volatile("s_waitcnt vmcnt(6)" ::: "memory");
    SCHED; SBAR;
    QD(1, 0);
    // P5
    rdA(1, 0); rdB(1); stgA(0, t2, 2);
    SCHED; SBAR;
    QD(0, 0);
    // P6
    stgB(1, t3, 0);
    SCHED; SBAR;
    QD(0, 1);
    // P7
    rdA(1, 1); stgB(1, t3, 2);
    SCHED; SBAR;
    QD(1, 1);
    // P8
    stgA(1, t3, 0);
    asm volatile("s_waitcnt vmcnt(6)" ::: "memory");
    SCHED; SBAR;
    QD(1, 0);
  }

  int shift = 0;
  if constexpr (MODE == 2) shift = (idxp[0] & 1) ? 256 : 0;

  const int rb0 = mt * 256 + wm * 128 + (g << 2);
  const int cbase = nt * 256 + wn * 64 + c15;
#pragma unroll
  for (int mi = 0; mi < 8; ++mi) {
    const int row = rb0 + mi * 16;
#pragma unroll
    for (int nj = 0; nj < 4; ++nj) {
      const int col = cbase + nj * 16;
      const float bvv = bias[col];
      if constexpr (MODE == 0) {
        u16* C = (u16*)Cp;
#pragma unroll
        for (int r = 0; r < 4; ++r)
          C[(size_t)(row + r) * N + col] = f2bf(acc[mi][nj][r] + bvv);
      } else if constexpr (MODE == 1) {
        u16* C = (u16*)Cp;
        const int hh = col >> 6, dd = col & 63;
        const int b_ = row >> 13, l_ = row & 8191;
        s16x4 pk;
#pragma unroll
        for (int r = 0; r < 4; ++r) pk[r] = (short)f2bf(acc[mi][nj][r] + bvv);
        *(s16x4*)(C + (((size_t)((b_ * 12 + hh) << 6) + dd) << 13) + l_) = pk;
      } else if constexpr (MODE == 2) {
        float* C = (float*)Cp;
        const int b_ = row >> 13, p_ = row & 8191;
        const int l0 = (p_ - shift) & 8191;
        const size_t rbase = ((size_t)((b_ << 1) + vview) << 13) + l0;
#pragma unroll
        for (int r = 0; r < 4; ++r) {
          const size_t idx = (rbase + r) * 768 + col;
          C[idx] = xres[idx] + acc[mi][nj][r] + bvv;
        }
      } else if constexpr (MODE == 3) {
        u16* C = (u16*)Cp;
#pragma unroll
        for (int r = 0; r < 4; ++r) {
          const float u = acc[mi][nj][r] + bvv;
          const float e = __builtin_amdgcn_exp2f(-2.45546693f * u);
          C[(size_t)(row + r) * N + col] = f2bf(u / (1.f + e));
        }
      } else {
        float* C = (float*)Cp;
#pragma unroll
        for (int r = 0; r < 4; ++r) {
          const size_t idx = (size_t)(row + r) * 768 + col;
          C[idx] = C[idx] + acc[mi][nj][r] + bvv;
        }
      }
    }
  }
}

// ---------------------------------------------------------------------------
// Windowed cross-view attention, LDS-staged K/V (r9, refcheck-passing).
// ---------------------------------------------------------------------------
__global__ __launch_bounds__(512, 2)
void attnk(const u16* __restrict__ Q1, const u16* __restrict__ K1, const u16* __restrict__ V1,
           const u16* __restrict__ Q2, const u16* __restrict__ K2, const u16* __restrict__ V2,
           u16* __restrict__ O, const int* __restrict__ idxp) {
  __shared__ char lds[131072];
  const int t = threadIdx.x;
  const int lane = t & 63;
  const int c = lane & 15, g = lane >> 4;
  const int wid = t >> 6;
  int bb = blockIdx.x;
  const int h = bb % 12; bb /= 12;
  const int w = bb & 15; bb >>= 4;
  const int b = bb & 3;
  const int a = bb >> 2;
  const int shift = (idxp[0] & 1) ? 256 : 0;

  const u16* Q  = a ? Q2 : Q1;
  const u16* Kb = a ? K2 : K1;
  const u16* Vt = a ? V2 : V1;
  const int kbase = b * 8192 + w * 512;
  const u16* Vts = Vt + ((size_t)(b * 12 + h) << 19);

  const int qrow0 = b * 8192 + w * 512 + wid * 64;
  bf16x8 qf[4][2];
#pragma unroll
  for (int q = 0; q < 4; ++q)
#pragma unroll
    for (int hf = 0; hf < 2; ++hf)
      qf[q][hf] = *(const bf16x8*)(Q + (size_t)(qrow0 + q * 16 + c) * 768 + h * 64 + hf * 32 + g * 8);

  {
    const int r0 = t >> 3, ch = t & 7;
    char* kdst = (char*)lds + (wid << 10);
#pragma unroll
    for (int p = 0; p < 8; ++p) {
      const int row = p * 64 + r0;
      gld_lds16(Kb + (size_t)(kbase + row) * 768 + h * 64 + ((ch ^ (row & 7)) << 3),
                kdst + p * 8192);
    }
    char* vdst = (char*)lds + 65536 + (wid << 10);
#pragma unroll
    for (int p = 0; p < 8; ++p) {
      const int vrow = p * 8 + wid;
      const int cg = lane ^ (vrow & 7);
      const int l = (w * 512 + cg * 8 - shift) & 8191;
      gld_lds16(Vts + (size_t)vrow * 8192 + l, vdst + p * 8192);
    }
  }
  __syncthreads();

  f32x4 oacc[4][4] = {};
  f32x4 psum[4] = {};
  const float CEXP = 0.125f * L2E;
  const char* LK = (char*)lds;
  const char* LV = (char*)lds + 65536;

  for (int kt = 0; kt < 32; ++kt) {
    const int krow = kt * 16 + c;
    const int ksw = krow & 7;
    const bf16x8 kf0 = *(const bf16x8*)(LK + krow * 128 + ((g ^ ksw) << 4));
    const bf16x8 kf1 = *(const bf16x8*)(LK + krow * 128 + (((4 | g) ^ ksw) << 4));
    s16x4 vf[4];
#pragma unroll
    for (int df = 0; df < 4; ++df) {
      const int vr = df * 16 + c;
      vf[df] = *(const s16x4*)(LV + vr * 1024 +
                               (((kt * 2 + (g >> 1)) ^ (vr & 7)) << 4) + ((g & 1) << 3));
    }

    const f32x4 z = {0.f, 0.f, 0.f, 0.f};
    s16x4 pk[4];
#pragma unroll
    for (int q = 0; q < 4; ++q) {
      f32x4 sc2 = __builtin_amdgcn_mfma_f32_16x16x32_bf16(kf0, qf[q][0], z, 0, 0, 0);
      sc2 = __builtin_amdgcn_mfma_f32_16x16x32_bf16(kf1, qf[q][1], sc2, 0, 0, 0);
      f32x4 pv;
      pv[0] = __builtin_amdgcn_exp2f(sc2[0] * CEXP);
      pv[1] = __builtin_amdgcn_exp2f(sc2[1] * CEXP);
      pv[2] = __builtin_amdgcn_exp2f(sc2[2] * CEXP);
      pv[3] = __builtin_amdgcn_exp2f(sc2[3] * CEXP);
      psum[q] += pv;
      pk[q][0] = (short)f2bf(pv[0]);
      pk[q][1] = (short)f2bf(pv[1]);
      pk[q][2] = (short)f2bf(pv[2]);
      pk[q][3] = (short)f2bf(pv[3]);
    }
#pragma unroll
    for (int df = 0; df < 4; ++df)
#pragma unroll
      for (int q = 0; q < 4; ++q)
        oacc[df][q] = __builtin_amdgcn_mfma_f32_16x16x16bf16_1k(vf[df], pk[q], oacc[df][q], 0, 0, 0);
  }

  const size_t orow0 = (size_t)(a * 32768 + qrow0);
#pragma unroll
  for (int q = 0; q < 4; ++q) {
    float ss = psum[q][0] + psum[q][1] + psum[q][2] + psum[q][3];
    ss += __shfl_xor(ss, 16);
    ss += __shfl_xor(ss, 32);
    const float inv = 1.f / ss;
#pragma unroll
    for (int df = 0; df < 4; ++df) {
      s16x4 po;
#pragma unroll
      for (int r = 0; r < 4; ++r) po[r] = (short)f2bf(oacc[df][q][r] * inv);
      *(s16x4*)(O + (orow0 + q * 16 + c) * 768 + h * 64 + df * 16 + g * 4) = po;
    }
  }
}

// ---------------------------------------------------------------------------
extern "C" void kernel_launch(void* const* d_in, const int* in_sizes, int n_in,
                              void* d_out, int out_size, void* d_ws, size_t ws_size,
                              hipStream_t stream) {
  const float* x       = (const float*)d_in[0];
  const float* ln1_g   = (const float*)d_in[1];
  const float* ln1_b   = (const float*)d_in[2];
  const float* ln2_g   = (const float*)d_in[3];
  const float* ln2_b   = (const float*)d_in[4];
  const float* a1_wqkv = (const float*)d_in[5];
  const float* a1_bqkv = (const float*)d_in[6];
  const float* a1_wo   = (const float*)d_in[7];
  const float* a1_bo   = (const float*)d_in[8];
  const float* a2_wqkv = (const float*)d_in[9];
  const float* a2_bqkv = (const float*)d_in[10];
  const float* a2_wo   = (const float*)d_in[11];
  const float* a2_bo   = (const float*)d_in[12];
  const float* fc_w    = (const float*)d_in[13];
  const float* fc_b    = (const float*)d_in[14];
  const float* proj_w  = (const float*)d_in[15];
  const float* proj_b  = (const float*)d_in[16];
  const int*   idxp    = (const int*)d_in[17];
  float* out = (float*)d_out;

  u16* p = (u16*)d_ws;
  u16* w1  = p; p += (size_t)2304 * 768;
  u16* w2  = p; p += (size_t)2304 * 768;
  u16* wo1 = p; p += (size_t)768 * 768;
  u16* wo2 = p; p += (size_t)768 * 768;
  u16* fcw = p; p += (size_t)3072 * 768;
  u16* pjw = p; p += (size_t)768 * 3072;
  u16* y   = p; p += (size_t)65536 * 768;
  u16* xv  = p; p += (size_t)65536 * 768;
  u16* Q1  = p; p += (size_t)32768 * 768;
  u16* K1  = p; p += (size_t)32768 * 768;
  u16* V1  = p; p += (size_t)32768 * 768;
  u16* Q2  = p; p += (size_t)32768 * 768;
  u16* K2  = p; p += (size_t)32768 * 768;
  u16* V2  = p; p += (size_t)32768 * 768;
  u16* Ob  = p; p += (size_t)65536 * 768;
  u16* hb  = Q1;  // MLP hidden aliases Q1..Ob

  cvtk<<<1728, 256, 0, stream>>>(a1_wqkv, w1, 2304 * 768);
  cvtk<<<1728, 256, 0, stream>>>(a2_wqkv, w2, 2304 * 768);
  cvtk<<<576,  256, 0, stream>>>(a1_wo, wo1, 768 * 768);
  cvtk<<<576,  256, 0, stream>>>(a2_wo, wo2, 768 * 768);
  cvtk<<<2304, 256, 0, stream>>>(fc_w, fcw, 3072 * 768);
  cvtk<<<2304, 256, 0, stream>>>(proj_w, pjw, 768 * 3072);

  lnk<<<16384, 256, 0, stream>>>(x, ln1_g, ln1_b, y, xv, 1);

  const size_t VS = (size_t)32768 * 768;
  gemm_bt<0><<<384, 512, 0, stream>>>(y,        w1,                  a1_bqkv,        Q1, 768, 768, nullptr, nullptr, 0);
  gemm_bt<0><<<384, 512, 0, stream>>>(y + VS,   w1 + 768 * 768,      a1_bqkv + 768,  K1, 768, 768, nullptr, nullptr, 0);
  gemm_bt<1><<<384, 512, 0, stream>>>(xv,       w1 + 2 * 768 * 768,  a1_bqkv + 1536, V1, 768, 768, nullptr, nullptr, 0);
  gemm_bt<0><<<384, 512, 0, stream>>>(y + VS,   w2,                  a2_bqkv,        Q2, 768, 768, nullptr, nullptr, 0);
  gemm_bt<0><<<384, 512, 0, stream>>>(y,        w2 + 768 * 768,      a2_bqkv + 768,  K2, 768, 768, nullptr, nullptr, 0);
  gemm_bt<1><<<384, 512, 0, stream>>>(xv + VS,  w2 + 2 * 768 * 768,  a2_bqkv + 1536, V2, 768, 768, nullptr, nullptr, 0);

  attnk<<<1536, 512, 0, stream>>>(Q1, K1, V1, Q2, K2, V2, Ob, idxp);

  gemm_bt<2><<<384, 512, 0, stream>>>(Ob,      wo1, a1_bo, out, 768, 768, x, idxp, 0);
  gemm_bt<2><<<384, 512, 0, stream>>>(Ob + VS, wo2, a2_bo, out, 768, 768, x, idxp, 1);

  lnk<<<16384, 256, 0, stream>>>(out, ln2_g, ln2_b, y, nullptr, 0);

  gemm_bt<3><<<3072, 512, 0, stream>>>(y, fcw, fc_b, hb, 3072, 768, nullptr, idxp, 0);

  gemm_bt<4><<<768, 512, 0, stream>>>(hb, pjw, proj_b, out, 768, 3072, nullptr, idxp, 0);
}

// Round 13
// 1372.007 us; speedup vs baseline: 1.3108x; 1.0615x over previous
//
#include <hip/hip_runtime.h>
#include <hip/hip_bf16.h>

typedef __bf16 bf16x8 __attribute__((ext_vector_type(8)));
typedef float  f32x4  __attribute__((ext_vector_type(4)));
typedef short  s16x4  __attribute__((ext_vector_type(4)));
typedef unsigned short u16;

#define L2E 1.44269504088896f
#define SBAR  __builtin_amdgcn_s_barrier()
#define SCHED __builtin_amdgcn_sched_barrier(0)

static __device__ __forceinline__ u16 f2bf(float f) {
  unsigned u = __builtin_bit_cast(unsigned, f);
  u += 0x7fffu + ((u >> 16) & 1u);
  return (u16)(u >> 16);
}

static __device__ __forceinline__ void gld_lds16(const void* g, void* l) {
  __builtin_amdgcn_global_load_lds((const __attribute__((address_space(1))) unsigned*)g,
                                   (__attribute__((address_space(3))) unsigned*)l, 16, 0, 0);
}

// ---------------------------------------------------------------------------
__global__ __launch_bounds__(256)
void cvtk(const float* __restrict__ s, u16* __restrict__ d, int n) {
  const int i = (blockIdx.x * 256 + threadIdx.x) * 4;
  if (i >= n) return;
  const float4 f = *(const float4*)(s + i);
  s16x4 p;
  p[0] = (short)f2bf(f.x); p[1] = (short)f2bf(f.y);
  p[2] = (short)f2bf(f.z); p[3] = (short)f2bf(f.w);
  *(s16x4*)(d + i) = p;
}

// ---------------------------------------------------------------------------
__global__ __launch_bounds__(256)
void lnk(const float* __restrict__ x, const float* __restrict__ gw,
         const float* __restrict__ bw, u16* __restrict__ y,
         u16* __restrict__ xv, int viewmajor) {
  const int lane = threadIdx.x & 63;
  const int tok = blockIdx.x * 4 + (threadIdx.x >> 6);
  const float* xr = x + (size_t)tok * 768;
  float4 v[3];
  float s = 0.f, sq = 0.f;
#pragma unroll
  for (int j = 0; j < 3; ++j) {
    v[j] = *(const float4*)(xr + j * 256 + lane * 4);
    s  += v[j].x + v[j].y + v[j].z + v[j].w;
    sq += v[j].x * v[j].x + v[j].y * v[j].y + v[j].z * v[j].z + v[j].w * v[j].w;
  }
#pragma unroll
  for (int o = 1; o < 64; o <<= 1) { s += __shfl_xor(s, o); sq += __shfl_xor(sq, o); }
  const float mean = s * (1.f / 768.f);
  const float var  = sq * (1.f / 768.f) - mean * mean;
  const float rstd = rsqrtf(var + 1e-5f);
  size_t yrow = (size_t)tok;
  if (viewmajor) {
    const int b_ = tok >> 14, vv = (tok >> 13) & 1, l_ = tok & 8191;
    yrow = ((size_t)((vv << 2) + b_) << 13) + l_;
  }
#pragma unroll
  for (int j = 0; j < 3; ++j) {
    const float4 g4 = *(const float4*)(gw + j * 256 + lane * 4);
    const float4 b4 = *(const float4*)(bw + j * 256 + lane * 4);
    s16x4 py;
    py[0] = (short)f2bf((v[j].x - mean) * rstd * g4.x + b4.x);
    py[1] = (short)f2bf((v[j].y - mean) * rstd * g4.y + b4.y);
    py[2] = (short)f2bf((v[j].z - mean) * rstd * g4.z + b4.z);
    py[3] = (short)f2bf((v[j].w - mean) * rstd * g4.w + b4.w);
    *(s16x4*)(y + yrow * 768 + j * 256 + lane * 4) = py;
    if (xv) {
      s16x4 px;
      px[0] = (short)f2bf(v[j].x); px[1] = (short)f2bf(v[j].y);
      px[2] = (short)f2bf(v[j].z); px[3] = (short)f2bf(v[j].w);
      *(s16x4*)(xv + yrow * 768 + j * 256 + lane * 4) = px;
    }
  }
}

// ---------------------------------------------------------------------------
// 8-phase GEMM, ONE barrier per phase (r12 core, best measured).
// BM=BN=256, BK=64, 8 waves (2Mx4N, per-wave 128x64), 2 K-tiles/iter,
// vmcnt(6) at P4/P8 only, XOR-swizzled LDS.
// MODE 3: C bf16 = gelu(acc+bias)                         (FC)
// MODE 4: out fp32 += acc+bias                            (proj residual)
// MODE 5: column-pair: nt<3 -> (B1,b1,C1) else (B2,b2,C2); C bf16 [row][768]
// MODE 6: V fused over M=65536: B/bias by mt<128; C1/C2 by row>>15,
//         transposed per-head Vt[b][h][64][8192]
// MODE 7: out-proj fused over M=65536: B/bias by mt<128; fp32 out =
//         x + acc + bias with window un-roll scatter (att = row>>15)
// ---------------------------------------------------------------------------
template<int MODE>
__global__ __launch_bounds__(512, 2)
void gemm_bt(const u16* __restrict__ A,
             const u16* __restrict__ B1, const u16* __restrict__ B2,
             const float* __restrict__ b1, const float* __restrict__ b2,
             void* __restrict__ C1, void* __restrict__ C2,
             int N, int K,
             const float* __restrict__ xres, const int* __restrict__ idxp) {
  __shared__ char lds[131072];
  const int t = threadIdx.x;
  const int lane = t & 63;
  const int wid = t >> 6;
  const int wm = wid >> 2, wn = wid & 3;

  const int cpx = gridDim.x >> 3;
  const int bid = (blockIdx.x & 7) * cpx + (blockIdx.x >> 3);
  const int Ntiles = N >> 8;
  const int PPB = Ntiles << 3;
  const int panel = bid / PPB;
  const int rem = bid - panel * PPB;
  const int nt = rem >> 3;
  const int mt = (panel << 3) + (rem & 7);

  // B / bias / local-nt selection
  const u16* Bsel = B1; const float* bias = b1; int ntl = nt;
  if constexpr (MODE == 5) {
    if (nt >= 3) { Bsel = B2; bias = b2; ntl = nt - 3; }
  } else if constexpr (MODE == 6 || MODE == 7) {
    if (mt >= 128) { Bsel = B2; bias = b2; }
  }

  const int urow = t >> 3;
  const int koff = ((t & 7) ^ (urow & 7)) << 3;
  const u16* Asrc = A + (size_t)(mt * 256 + urow) * K + koff;
  const u16* Bsrc = Bsel + (size_t)(ntl * 256 + urow) * K + koff;
  const int wdst = wid << 10;

  auto stgA = [&](int d, int kt, int u0) {
    char* base = (char*)lds + d * 32768 + wdst;
    gld_lds16(Asrc + (size_t)(u0 * 64) * K + kt * 64, base + u0 * 8192);
    gld_lds16(Asrc + (size_t)(u0 * 64 + 64) * K + kt * 64, base + u0 * 8192 + 8192);
  };
  auto stgB = [&](int d, int kt, int u0) {
    char* base = (char*)lds + 65536 + d * 32768 + wdst;
    gld_lds16(Bsrc + (size_t)(u0 * 64) * K + kt * 64, base + u0 * 8192);
    gld_lds16(Bsrc + (size_t)(u0 * 64 + 64) * K + kt * 64, base + u0 * 8192 + 8192);
  };

  const int c15 = lane & 15, g = lane >> 4;
  const int axor = c15 & 7;
  const char* LAb = (char*)lds + (wm * 128 + c15) * 128;
  const char* LBb = (char*)lds + 65536 + (wn * 64 + c15) * 128;
  bf16x8 av[4][2], bv[4][2];
  auto rdA = [&](int d, int mh) {
#pragma unroll
    for (int m = 0; m < 4; ++m)
#pragma unroll
      for (int ks = 0; ks < 2; ++ks)
        av[m][ks] = *(const bf16x8*)(LAb + d * 32768 + (mh * 64 + m * 16) * 128 +
                                     (((ks << 2) | g) ^ axor) * 16);
  };
  auto rdB = [&](int d) {
#pragma unroll
    for (int n = 0; n < 4; ++n)
#pragma unroll
      for (int ks = 0; ks < 2; ++ks)
        bv[n][ks] = *(const bf16x8*)(LBb + d * 32768 + (n * 16) * 128 +
                                     (((ks << 2) | g) ^ axor) * 16);
  };

  f32x4 acc[8][4] = {};
  auto QD = [&](int mh, int nh) {
    __builtin_amdgcn_s_setprio(1);
#pragma unroll
    for (int ks = 0; ks < 2; ++ks)
#pragma unroll
      for (int m = 0; m < 4; ++m)
#pragma unroll
        for (int n = 0; n < 2; ++n)
          acc[mh * 4 + m][nh * 2 + n] = __builtin_amdgcn_mfma_f32_16x16x32_bf16(
              av[m][ks], bv[nh * 2 + n][ks], acc[mh * 4 + m][nh * 2 + n], 0, 0, 0);
    __builtin_amdgcn_s_setprio(0);
  };

  const int nk = K >> 6, niter = nk >> 1, last = nk - 1;

  stgA(0, 0, 0); stgA(0, 0, 2); stgB(0, 0, 0); stgB(0, 0, 2);
  stgB(1, 1, 0); stgB(1, 1, 2); stgA(1, 1, 0);
  asm volatile("s_waitcnt vmcnt(6)" ::: "memory");
  SBAR;

  for (int it = 0; it < niter; ++it) {
    const int i2 = it * 2;
    const int t1 = (i2 + 1 < nk) ? i2 + 1 : last;
    const int t2 = (i2 + 2 < nk) ? i2 + 2 : last;
    const int t3 = (i2 + 3 < nk) ? i2 + 3 : last;

    rdA(0, 0); rdB(0); stgA(1, t1, 2);
    SCHED; SBAR;
    QD(0, 0);
    stgB(0, t2, 0);
    SCHED; SBAR;
    QD(0, 1);
    rdA(0, 1); stgB(0, t2, 2);
    SCHED; SBAR;
    QD(1, 1);
    stgA(0, t2, 0);
    asm volatile("s_waitcnt vmcnt(6)" ::: "memory");
    SCHED; SBAR;
    QD(1, 0);
    rdA(1, 0); rdB(1); stgA(0, t2, 2);
    SCHED; SBAR;
    QD(0, 0);
    stgB(1, t3, 0);
    SCHED; SBAR;
    QD(0, 1);
    rdA(1, 1); stgB(1, t3, 2);
    SCHED; SBAR;
    QD(1, 1);
    stgA(1, t3, 0);
    asm volatile("s_waitcnt vmcnt(6)" ::: "memory");
    SCHED; SBAR;
    QD(1, 0);
  }

  int shift = 0;
  if constexpr (MODE == 7) shift = (idxp[0] & 1) ? 256 : 0;

  const int rb0 = mt * 256 + wm * 128 + (g << 2);
  const int cb_nt = (MODE == 5) ? ntl : nt;
  const int cbase = cb_nt * 256 + wn * 64 + c15;
#pragma unroll
  for (int mi = 0; mi < 8; ++mi) {
    const int row = rb0 + mi * 16;
#pragma unroll
    for (int nj = 0; nj < 4; ++nj) {
      const int col = cbase + nj * 16;
      const float bvv = bias[col];
      if constexpr (MODE == 3) {
        u16* C = (u16*)C1;
#pragma unroll
        for (int r = 0; r < 4; ++r) {
          const float u = acc[mi][nj][r] + bvv;
          const float e = __builtin_amdgcn_exp2f(-2.45546693f * u);
          C[(size_t)(row + r) * N + col] = f2bf(u / (1.f + e));
        }
      } else if constexpr (MODE == 4) {
        float* C = (float*)C1;
#pragma unroll
        for (int r = 0; r < 4; ++r) {
          const size_t idx = (size_t)(row + r) * 768 + col;
          C[idx] = C[idx] + acc[mi][nj][r] + bvv;
        }
      } else if constexpr (MODE == 5) {
        u16* C = (u16*)(nt >= 3 ? C2 : C1);
#pragma unroll
        for (int r = 0; r < 4; ++r)
          C[(size_t)(row + r) * 768 + col] = f2bf(acc[mi][nj][r] + bvv);
      } else if constexpr (MODE == 6) {
        u16* C = (u16*)(row >= 32768 ? C2 : C1);
        const int r32 = row & 32767;
        const int hh = col >> 6, dd = col & 63;
        const int b_ = r32 >> 13, l_ = r32 & 8191;
        s16x4 pk;
#pragma unroll
        for (int r = 0; r < 4; ++r) pk[r] = (short)f2bf(acc[mi][nj][r] + bvv);
        *(s16x4*)(C + (((size_t)((b_ * 12 + hh) << 6) + dd) << 13) + l_) = pk;
      } else {  // MODE 7
        float* C = (float*)C1;
        const int att = row >> 15;
        const int r32 = row & 32767;
        const int b_ = r32 >> 13, p_ = r32 & 8191;
        const int l0 = (p_ - shift) & 8191;
        const size_t rbase = ((size_t)((b_ << 1) + att) << 13) + l0;
#pragma unroll
        for (int r = 0; r < 4; ++r) {
          const size_t idx = (rbase + r) * 768 + col;
          C[idx] = xres[idx] + acc[mi][nj][r] + bvv;
        }
      }
    }
  }
}

// ---------------------------------------------------------------------------
// Windowed cross-view attention, LDS-staged K/V (r9, refcheck-passing).
// ---------------------------------------------------------------------------
__global__ __launch_bounds__(512, 2)
void attnk(const u16* __restrict__ Q1, const u16* __restrict__ K1, const u16* __restrict__ V1,
           const u16* __restrict__ Q2, const u16* __restrict__ K2, const u16* __restrict__ V2,
           u16* __restrict__ O, const int* __restrict__ idxp) {
  __shared__ char lds[131072];
  const int t = threadIdx.x;
  const int lane = t & 63;
  const int c = lane & 15, g = lane >> 4;
  const int wid = t >> 6;
  int bb = blockIdx.x;
  const int h = bb % 12; bb /= 12;
  const int w = bb & 15; bb >>= 4;
  const int b = bb & 3;
  const int a = bb >> 2;
  const int shift = (idxp[0] & 1) ? 256 : 0;

  const u16* Q  = a ? Q2 : Q1;
  const u16* Kb = a ? K2 : K1;
  const u16* Vt = a ? V2 : V1;
  const int kbase = b * 8192 + w * 512;
  const u16* Vts = Vt + ((size_t)(b * 12 + h) << 19);

  const int qrow0 = b * 8192 + w * 512 + wid * 64;
  bf16x8 qf[4][2];
#pragma unroll
  for (int q = 0; q < 4; ++q)
#pragma unroll
    for (int hf = 0; hf < 2; ++hf)
      qf[q][hf] = *(const bf16x8*)(Q + (size_t)(qrow0 + q * 16 + c) * 768 + h * 64 + hf * 32 + g * 8);

  {
    const int r0 = t >> 3, ch = t & 7;
    char* kdst = (char*)lds + (wid << 10);
#pragma unroll
    for (int p = 0; p < 8; ++p) {
      const int row = p * 64 + r0;
      gld_lds16(Kb + (size_t)(kbase + row) * 768 + h * 64 + ((ch ^ (row & 7)) << 3),
                kdst + p * 8192);
    }
    char* vdst = (char*)lds + 65536 + (wid << 10);
#pragma unroll
    for (int p = 0; p < 8; ++p) {
      const int vrow = p * 8 + wid;
      const int cg = lane ^ (vrow & 7);
      const int l = (w * 512 + cg * 8 - shift) & 8191;
      gld_lds16(Vts + (size_t)vrow * 8192 + l, vdst + p * 8192);
    }
  }
  __syncthreads();

  f32x4 oacc[4][4] = {};
  f32x4 psum[4] = {};
  const float CEXP = 0.125f * L2E;
  const char* LK = (char*)lds;
  const char* LV = (char*)lds + 65536;

  for (int kt = 0; kt < 32; ++kt) {
    const int krow = kt * 16 + c;
    const int ksw = krow & 7;
    const bf16x8 kf0 = *(const bf16x8*)(LK + krow * 128 + ((g ^ ksw) << 4));
    const bf16x8 kf1 = *(const bf16x8*)(LK + krow * 128 + (((4 | g) ^ ksw) << 4));
    s16x4 vf[4];
#pragma unroll
    for (int df = 0; df < 4; ++df) {
      const int vr = df * 16 + c;
      vf[df] = *(const s16x4*)(LV + vr * 1024 +
                               (((kt * 2 + (g >> 1)) ^ (vr & 7)) << 4) + ((g & 1) << 3));
    }

    const f32x4 z = {0.f, 0.f, 0.f, 0.f};
    s16x4 pk[4];
#pragma unroll
    for (int q = 0; q < 4; ++q) {
      f32x4 sc2 = __builtin_amdgcn_mfma_f32_16x16x32_bf16(kf0, qf[q][0], z, 0, 0, 0);
      sc2 = __builtin_amdgcn_mfma_f32_16x16x32_bf16(kf1, qf[q][1], sc2, 0, 0, 0);
      f32x4 pv;
      pv[0] = __builtin_amdgcn_exp2f(sc2[0] * CEXP);
      pv[1] = __builtin_amdgcn_exp2f(sc2[1] * CEXP);
      pv[2] = __builtin_amdgcn_exp2f(sc2[2] * CEXP);
      pv[3] = __builtin_amdgcn_exp2f(sc2[3] * CEXP);
      psum[q] += pv;
      pk[q][0] = (short)f2bf(pv[0]);
      pk[q][1] = (short)f2bf(pv[1]);
      pk[q][2] = (short)f2bf(pv[2]);
      pk[q][3] = (short)f2bf(pv[3]);
    }
#pragma unroll
    for (int df = 0; df < 4; ++df)
#pragma unroll
      for (int q = 0; q < 4; ++q)
        oacc[df][q] = __builtin_amdgcn_mfma_f32_16x16x16bf16_1k(vf[df], pk[q], oacc[df][q], 0, 0, 0);
  }

  const size_t orow0 = (size_t)(a * 32768 + qrow0);
#pragma unroll
  for (int q = 0; q < 4; ++q) {
    float ss = psum[q][0] + psum[q][1] + psum[q][2] + psum[q][3];
    ss += __shfl_xor(ss, 16);
    ss += __shfl_xor(ss, 32);
    const float inv = 1.f / ss;
#pragma unroll
    for (int df = 0; df < 4; ++df) {
      s16x4 po;
#pragma unroll
      for (int r = 0; r < 4; ++r) po[r] = (short)f2bf(oacc[df][q][r] * inv);
      *(s16x4*)(O + (orow0 + q * 16 + c) * 768 + h * 64 + df * 16 + g * 4) = po;
    }
  }
}

// ---------------------------------------------------------------------------
extern "C" void kernel_launch(void* const* d_in, const int* in_sizes, int n_in,
                              void* d_out, int out_size, void* d_ws, size_t ws_size,
                              hipStream_t stream) {
  const float* x       = (const float*)d_in[0];
  const float* ln1_g   = (const float*)d_in[1];
  const float* ln1_b   = (const float*)d_in[2];
  const float* ln2_g   = (const float*)d_in[3];
  const float* ln2_b   = (const float*)d_in[4];
  const float* a1_wqkv = (const float*)d_in[5];
  const float* a1_bqkv = (const float*)d_in[6];
  const float* a1_wo   = (const float*)d_in[7];
  const float* a1_bo   = (const float*)d_in[8];
  const float* a2_wqkv = (const float*)d_in[9];
  const float* a2_bqkv = (const float*)d_in[10];
  const float* a2_wo   = (const float*)d_in[11];
  const float* a2_bo   = (const float*)d_in[12];
  const float* fc_w    = (const float*)d_in[13];
  const float* fc_b    = (const float*)d_in[14];
  const float* proj_w  = (const float*)d_in[15];
  const float* proj_b  = (const float*)d_in[16];
  const int*   idxp    = (const int*)d_in[17];
  float* out = (float*)d_out;

  u16* p = (u16*)d_ws;
  u16* w1  = p; p += (size_t)2304 * 768;
  u16* w2  = p; p += (size_t)2304 * 768;
  u16* wo1 = p; p += (size_t)768 * 768;
  u16* wo2 = p; p += (size_t)768 * 768;
  u16* fcw = p; p += (size_t)3072 * 768;
  u16* pjw = p; p += (size_t)768 * 3072;
  u16* y   = p; p += (size_t)65536 * 768;
  u16* xv  = p; p += (size_t)65536 * 768;
  u16* Q1  = p; p += (size_t)32768 * 768;
  u16* K1  = p; p += (size_t)32768 * 768;
  u16* V1  = p; p += (size_t)32768 * 768;
  u16* Q2  = p; p += (size_t)32768 * 768;
  u16* K2  = p; p += (size_t)32768 * 768;
  u16* V2  = p; p += (size_t)32768 * 768;
  u16* Ob  = p; p += (size_t)65536 * 768;
  u16* hb  = Q1;  // MLP hidden aliases Q1..Ob

  cvtk<<<1728, 256, 0, stream>>>(a1_wqkv, w1, 2304 * 768);
  cvtk<<<1728, 256, 0, stream>>>(a2_wqkv, w2, 2304 * 768);
  cvtk<<<576,  256, 0, stream>>>(a1_wo, wo1, 768 * 768);
  cvtk<<<576,  256, 0, stream>>>(a2_wo, wo2, 768 * 768);
  cvtk<<<2304, 256, 0, stream>>>(fc_w, fcw, 3072 * 768);
  cvtk<<<2304, 256, 0, stream>>>(proj_w, pjw, 768 * 3072);

  lnk<<<16384, 256, 0, stream>>>(x, ln1_g, ln1_b, y, xv, 1);

  const size_t VS = (size_t)32768 * 768;

  // d1: [Q1 | K2] from y0 (M=32768, N=1536) -> 768 blocks, 3 full gens
  gemm_bt<5><<<768, 512, 0, stream>>>(y, w1, w2 + 768 * 768,
                                      a1_bqkv, a2_bqkv + 768,
                                      Q1, K2, 1536, 768, nullptr, idxp);
  // d2: [K1 | Q2] from y1
  gemm_bt<5><<<768, 512, 0, stream>>>(y + VS, w1 + 768 * 768, w2,
                                      a1_bqkv + 768, a2_bqkv,
                                      K1, Q2, 1536, 768, nullptr, idxp);
  // d3: V1+V2 fused over M=65536 (A = xv contiguous; B/bias by row-half)
  gemm_bt<6><<<768, 512, 0, stream>>>(xv, w1 + 2 * 768 * 768, w2 + 2 * 768 * 768,
                                      a1_bqkv + 1536, a2_bqkv + 1536,
                                      V1, V2, 768, 768, nullptr, idxp);

  attnk<<<1536, 512, 0, stream>>>(Q1, K1, V1, Q2, K2, V2, Ob, idxp);

  // d4: out-proj fused over M=65536 + residual scatter -> d_out
  gemm_bt<7><<<768, 512, 0, stream>>>(Ob, wo1, wo2, a1_bo, a2_bo,
                                      out, nullptr, 768, 768, x, idxp);

  lnk<<<16384, 256, 0, stream>>>(out, ln2_g, ln2_b, y, nullptr, 0);

  gemm_bt<3><<<3072, 512, 0, stream>>>(y, fcw, nullptr, fc_b, nullptr,
                                       hb, nullptr, 3072, 768, nullptr, idxp);

  gemm_bt<4><<<768, 512, 0, stream>>>(hb, pjw, nullptr, proj_b, nullptr,
                                      out, nullptr, 768, 3072, nullptr, idxp);
}